// Round 6
// baseline (296.287 us; speedup 1.0000x reference)
//
#include <hip/hip_runtime.h>
#include <hip/hip_bf16.h>

#define N_FEAT 3072
#define LATENT 128
#define LOG2PI 1.8378770664093453f

typedef __attribute__((ext_vector_type(8))) short short8;
typedef __attribute__((ext_vector_type(4))) float f32x4;

__device__ __forceinline__ unsigned short f2bf(float x) {
  unsigned int u = __float_as_uint(x);
  u += 0x7FFFu + ((u >> 16) & 1u);
  return (unsigned short)(u >> 16);
}

// async global->LDS DMA, 16B per lane; lds base must be wave-uniform
#define GLL(g, l)                                                        \
  __builtin_amdgcn_global_load_lds(                                      \
      (__attribute__((address_space(1))) void*)(g),                      \
      (__attribute__((address_space(3))) void*)(l), 16, 0, 0)

// ---------------------------------------------------------------------------
// k_prep: (a) M += Wchunk^T Wchunk (atomics, M pre-zeroed)
//         (b) Wt[n][k] = bf16(W[k][n])
//         (c) tmu[j] += sum_k W[k][j]*mean[k];  scal[2] += sum mean^2
// 48 blocks x 64 k-rows; W read once.  (proven round 4/5)
// ---------------------------------------------------------------------------
#define GR_CHUNK 64
__global__ __launch_bounds__(256) void k_prep(const float* __restrict__ W,
                                              const float* __restrict__ mean,
                                              float* __restrict__ M,
                                              unsigned short* __restrict__ Wt,
                                              float* __restrict__ tmu,
                                              float* __restrict__ scal) {
  __shared__ __align__(16) float Ws[GR_CHUNK * 128];
  int t = threadIdx.x;
  int k0 = blockIdx.x * GR_CHUNK;
  const float* src = W + (size_t)k0 * 128;
#pragma unroll
  for (int c = 0; c < 8; ++c)
    ((float4*)Ws)[t + 256 * c] = ((const float4*)src)[t + 256 * c];
  __syncthreads();
  int tr = t >> 4, tc = t & 15;
  float acc[8][8];
#pragma unroll
  for (int r = 0; r < 8; ++r)
#pragma unroll
    for (int c = 0; c < 8; ++c) acc[r][c] = 0.f;
#pragma unroll 2
  for (int k = 0; k < GR_CHUNK; ++k) {
    f32x4 a0 = *(f32x4*)&Ws[k * 128 + 8 * tr];
    f32x4 a1 = *(f32x4*)&Ws[k * 128 + 8 * tr + 4];
    f32x4 b0 = *(f32x4*)&Ws[k * 128 + 8 * tc];
    f32x4 b1 = *(f32x4*)&Ws[k * 128 + 8 * tc + 4];
    float av[8] = {a0.x, a0.y, a0.z, a0.w, a1.x, a1.y, a1.z, a1.w};
    float bv[8] = {b0.x, b0.y, b0.z, b0.w, b1.x, b1.y, b1.z, b1.w};
#pragma unroll
    for (int r = 0; r < 8; ++r)
#pragma unroll
      for (int c = 0; c < 8; ++c) acc[r][c] = fmaf(av[r], bv[c], acc[r][c]);
  }
  float* dst = M + (size_t)(8 * tr) * 128 + 8 * tc;
#pragma unroll
  for (int r = 0; r < 8; ++r)
#pragma unroll
    for (int c = 0; c < 8; ++c) atomicAdd(&dst[r * 128 + c], acc[r][c]);
  int n = t >> 1, h = t & 1;
  unsigned pk[16];
#pragma unroll
  for (int c = 0; c < 16; ++c)
    pk[c] = (unsigned)f2bf(Ws[(h * 32 + 2 * c) * 128 + n]) |
            ((unsigned)f2bf(Ws[(h * 32 + 2 * c + 1) * 128 + n]) << 16);
  uint4* wd = (uint4*)(Wt + (size_t)n * N_FEAT + k0 + h * 32);
#pragma unroll
  for (int c = 0; c < 4; ++c)
    wd[c] = make_uint4(pk[4 * c], pk[4 * c + 1], pk[4 * c + 2], pk[4 * c + 3]);
  if (t < 128) {
    float tm = 0.f;
#pragma unroll 8
    for (int k = 0; k < GR_CHUNK; ++k)
      tm = fmaf(Ws[k * 128 + t], mean[k0 + k], tm);
    atomicAdd(&tmu[t], tm);
  } else if (t == 128) {
    float s = 0.f;
#pragma unroll 8
    for (int k = 0; k < GR_CHUNK; ++k) {
      float m = mean[k0 + k];
      s = fmaf(m, m, s);
    }
    atomicAdd(&scal[2], s);
  }
}

// ---------------------------------------------------------------------------
// k_packinv (512 thr): blocks 0..1023: pack 8 rows each (Xb, ssq, xmu).
//   block 1024: BLOCKED Gauss-Jordan inverse of M + sigma^2 I with 8x8 pivot
//   blocks -> 16 steps x 3 barriers (vs 128 steps before). Every thread
//   redundantly inverts the 8x8 pivot in registers (static indices), then
//   128 threads form Pinv*R, 128 form -C*Pinv, then rank-8 update on 8x4
//   register tiles. logf off the critical path (parallel reduce at end).
// ---------------------------------------------------------------------------
__global__ __launch_bounds__(512) void k_packinv(const float* __restrict__ ex,
                                                 const float* __restrict__ mean,
                                                 unsigned short* __restrict__ Xb,
                                                 float* __restrict__ ssq,
                                                 float* __restrict__ xmu,
                                                 float* __restrict__ M,
                                                 float* __restrict__ scal,
                                                 const float* __restrict__ log_var) {
  int t = threadIdx.x;
  if (blockIdx.x == 1024) {
    // ---------------- blocked inverse path ----------------
    __shared__ __align__(16) float Rs[8][128];    // raw pivot rows
    __shared__ __align__(16) float Rp[8][128];    // Pinv * R
    __shared__ __align__(16) float CsT[8][136];   // raw pivot cols, transposed
    __shared__ __align__(16) float CpT[8][136];   // -C * Pinv, transposed
    __shared__ float diag[128];
    __shared__ float red[8];
    int tr = t >> 5;   // 0..15 : rows 8tr..8tr+7
    int tc = t & 31;   // 0..31 : cols 4tc..4tc+3
    float lv = log_var[0];
    float sig2 = expf(lv);
    float a[8][4];
    const float* srcM = M + (size_t)(8 * tr) * 128 + 4 * tc;
#pragma unroll
    for (int r = 0; r < 8; ++r) {
      f32x4 v = *(const f32x4*)(srcM + r * 128);
      a[r][0] = v.x; a[r][1] = v.y; a[r][2] = v.z; a[r][3] = v.w;
    }
#pragma unroll
    for (int r = 0; r < 8; ++r)
#pragma unroll
      for (int c = 0; c < 4; ++c)
        if (8 * tr + r == 4 * tc + c) a[r][c] += sig2;

    for (int kb = 0; kb < 16; ++kb) {
      // ---- phase 1: stage raw pivot rows/cols ----
      if (tr == kb) {
#pragma unroll
        for (int r = 0; r < 8; ++r)
          *(f32x4*)&Rs[r][4 * tc] = (f32x4){a[r][0], a[r][1], a[r][2], a[r][3]};
      }
      if ((tc >> 1) == kb) {
        int jb = (tc & 1) * 4;
#pragma unroll
        for (int r = 0; r < 8; ++r)
#pragma unroll
          for (int c = 0; c < 4; ++c) CsT[jb + c][8 * tr + r] = a[r][c];
      }
      __syncthreads();
      // ---- phase 2: redundant 8x8 pivot inverse (compact GJ, in place) ----
      float P[8][8];
#pragma unroll
      for (int i = 0; i < 8; ++i) {
        f32x4 p0 = *(const f32x4*)&Rs[i][8 * kb];
        f32x4 p1 = *(const f32x4*)&Rs[i][8 * kb + 4];
        P[i][0] = p0.x; P[i][1] = p0.y; P[i][2] = p0.z; P[i][3] = p0.w;
        P[i][4] = p1.x; P[i][5] = p1.y; P[i][6] = p1.z; P[i][7] = p1.w;
      }
#pragma unroll
      for (int i = 0; i < 8; ++i) {
        float d = P[i][i];
        if (t == 0) diag[8 * kb + i] = d;
        float pi = 1.0f / d;
        P[i][i] = 1.0f;
#pragma unroll
        for (int c = 0; c < 8; ++c) P[i][c] *= pi;
#pragma unroll
        for (int r = 0; r < 8; ++r) {
          if (r == i) continue;
          float e = P[r][i];
          P[r][i] = 0.0f;
#pragma unroll
          for (int c = 0; c < 8; ++c) P[r][c] = fmaf(-e, P[i][c], P[r][c]);
        }
      }
      // Rp = Pinv * R (threads 0..127, one column each; static Pinv indices)
      if (t < 128) {
        float rcol[8];
#pragma unroll
        for (int m = 0; m < 8; ++m) rcol[m] = Rs[m][t];
#pragma unroll
        for (int i = 0; i < 8; ++i) {
          float s = 0.f;
#pragma unroll
          for (int m = 0; m < 8; ++m) s = fmaf(P[i][m], rcol[m], s);
          Rp[i][t] = s;
        }
      } else if (t < 256) {
        // CpT = -(C * Pinv)^T (threads 128..255, one row of C each)
        int r = t - 128;
        float crow[8];
#pragma unroll
        for (int m = 0; m < 8; ++m) crow[m] = CsT[m][r];
#pragma unroll
        for (int j = 0; j < 8; ++j) {
          float s = 0.f;
#pragma unroll
          for (int m = 0; m < 8; ++m) s = fmaf(crow[m], P[m][j], s);
          CpT[j][r] = -s;
        }
      }
      __syncthreads();
      // ---- phase 3: rank-8 update + fixups ----
      float cl[8][8], rp[8][4];
#pragma unroll
      for (int m = 0; m < 8; ++m) {
        f32x4 c0 = *(const f32x4*)&CsT[m][8 * tr];
        f32x4 c1 = *(const f32x4*)&CsT[m][8 * tr + 4];
        cl[0][m] = c0.x; cl[1][m] = c0.y; cl[2][m] = c0.z; cl[3][m] = c0.w;
        cl[4][m] = c1.x; cl[5][m] = c1.y; cl[6][m] = c1.z; cl[7][m] = c1.w;
        f32x4 rv = *(const f32x4*)&Rp[m][4 * tc];
        rp[m][0] = rv.x; rp[m][1] = rv.y; rp[m][2] = rv.z; rp[m][3] = rv.w;
      }
#pragma unroll
      for (int r = 0; r < 8; ++r)
#pragma unroll
        for (int c = 0; c < 4; ++c) {
          float s = a[r][c];
#pragma unroll
          for (int m = 0; m < 8; ++m) s = fmaf(-cl[r][m], rp[m][c], s);
          a[r][c] = s;
        }
      if (tr == kb) {
#pragma unroll
        for (int r = 0; r < 8; ++r)
#pragma unroll
          for (int c = 0; c < 4; ++c) a[r][c] = rp[r][c];
      }
      if ((tc >> 1) == kb) {
        int jb = (tc & 1) * 4;
#pragma unroll
        for (int r = 0; r < 8; ++r)
#pragma unroll
          for (int c = 0; c < 4; ++c) a[r][c] = CpT[jb + c][8 * tr + r];
        if (tr == kb) {
          if ((tc & 1) == 0) {
#pragma unroll
            for (int r = 0; r < 8; ++r)
#pragma unroll
              for (int c = 0; c < 4; ++c) a[r][c] = P[r][c];
          } else {
#pragma unroll
            for (int r = 0; r < 8; ++r)
#pragma unroll
              for (int c = 0; c < 4; ++c) a[r][c] = P[r][4 + c];
          }
        }
      }
      __syncthreads();
    }

    float* dstM = M + (size_t)(8 * tr) * 128 + 4 * tc;
#pragma unroll
    for (int r = 0; r < 8; ++r)
      *(f32x4*)(dstM + r * 128) = (f32x4){a[r][0], a[r][1], a[r][2], a[r][3]};
    // parallel logdet
    float ld = 0.f;
    if (t < 128) ld = logf(diag[t]);
#pragma unroll
    for (int o = 1; o < 64; o <<= 1) ld += __shfl_xor(ld, o);
    if (t == 0) red[0] = ld;
    if (t == 64) red[1] = ld;
    __syncthreads();
    if (t == 0) {
      scal[0] = -0.5f * (N_FEAT * LOG2PI + (float)(N_FEAT - LATENT) * lv +
                         (red[0] + red[1]));
      scal[1] = expf(-lv);
    }
    return;
  }

  // ---------------- pack path (streaming, barrier-free) ----------------
  int w = t >> 6, l = t & 63;
  int row = blockIdx.x * 8 + w;
  const float* xp = ex + (size_t)row * N_FEAT;
  unsigned short* op = Xb + (size_t)row * N_FEAT;
  float sq = 0.f, dm = 0.f;
#pragma unroll
  for (int c = 0; c < 6; ++c) {
    int off = c * 512 + l * 8;
    float4 x0 = *(const float4*)(xp + off);
    float4 x1 = *(const float4*)(xp + off + 4);
    float4 m0 = *(const float4*)(mean + off);
    float4 m1 = *(const float4*)(mean + off + 4);
    sq = fmaf(x0.x, x0.x, sq); sq = fmaf(x0.y, x0.y, sq);
    sq = fmaf(x0.z, x0.z, sq); sq = fmaf(x0.w, x0.w, sq);
    sq = fmaf(x1.x, x1.x, sq); sq = fmaf(x1.y, x1.y, sq);
    sq = fmaf(x1.z, x1.z, sq); sq = fmaf(x1.w, x1.w, sq);
    dm = fmaf(x0.x, m0.x, dm); dm = fmaf(x0.y, m0.y, dm);
    dm = fmaf(x0.z, m0.z, dm); dm = fmaf(x0.w, m0.w, dm);
    dm = fmaf(x1.x, m1.x, dm); dm = fmaf(x1.y, m1.y, dm);
    dm = fmaf(x1.z, m1.z, dm); dm = fmaf(x1.w, m1.w, dm);
    uint4 pk;
    pk.x = (unsigned)f2bf(x0.x) | ((unsigned)f2bf(x0.y) << 16);
    pk.y = (unsigned)f2bf(x0.z) | ((unsigned)f2bf(x0.w) << 16);
    pk.z = (unsigned)f2bf(x1.x) | ((unsigned)f2bf(x1.y) << 16);
    pk.w = (unsigned)f2bf(x1.z) | ((unsigned)f2bf(x1.w) << 16);
    *(uint4*)(op + off) = pk;
  }
#pragma unroll
  for (int o = 1; o < 64; o <<= 1) {
    sq += __shfl_xor(sq, o);
    dm += __shfl_xor(dm, o);
  }
  if (l == 0) {
    ssq[row] = sq;
    xmu[row] = dm;
  }
}

// ---------------------------------------------------------------------------
// k_gemm: T-tile = Xb * Wt^T (m97-style DMA K-loop) + fused quad epilogue.
// (unchanged from round 5)
// ---------------------------------------------------------------------------
__global__ __launch_bounds__(512) void k_gemm(const unsigned short* __restrict__ Xb,
                                              const unsigned short* __restrict__ Wt,
                                              const float* __restrict__ Minv,
                                              const float* __restrict__ ssq,
                                              const float* __restrict__ xmu,
                                              const float* __restrict__ tmu,
                                              const float* __restrict__ scal,
                                              float* __restrict__ out) {
  __shared__ __align__(16) unsigned short As[2][32][128];
  __shared__ __align__(16) unsigned short Bs[2][128][128];
  __shared__ __align__(16) float Ts[32][132];
  __shared__ float tm[128];
  __shared__ float rs[32];
  int t = threadIdx.x;
  int l = t & 63, w = t >> 6;
  int wr = w & 1, wc = w >> 1;
  int fr = l & 15, fq = l >> 4;
  int r0 = blockIdx.x * 32;
  int lr = l >> 4, lk = l & 15;

  if (t < 128) tm[t] = tmu[t];

  int arow = 4 * w + lr;
  const unsigned short* ga =
      Xb + (size_t)(r0 + arow) * N_FEAT + (lk ^ (arow & 7)) * 8;
  unsigned short* la = &As[0][4 * w][0];
  const unsigned short* gb[4];
  unsigned short* lb[4];
#pragma unroll
  for (int i = 0; i < 4; ++i) {
    int br = 4 * w + 32 * i + lr;
    gb[i] = Wt + (size_t)br * N_FEAT + (lk ^ (br & 7)) * 8;
    lb[i] = &Bs[0][4 * w + 32 * i][0];
  }

  GLL(ga, la);
#pragma unroll
  for (int i = 0; i < 4; ++i) GLL(gb[i], lb[i]);

  int ar = wr * 16 + fr;
  int arm = ar & 7;
  int n0 = wc * 32 + fr, n1 = n0 + 16;
  int nm0 = n0 & 7, nm1 = n1 & 7;
  const unsigned short* Ab = &As[0][ar][0];
  const unsigned short* Bb0 = &Bs[0][n0][0];
  const unsigned short* Bb1 = &Bs[0][n1][0];

  f32x4 acc0 = {0.f, 0.f, 0.f, 0.f}, acc1 = {0.f, 0.f, 0.f, 0.f};

  for (int it = 0; it < 24; ++it) {
    const int buf = it & 1;
    __syncthreads();
    if (it + 1 < 24) {
      const int nb = buf ^ 1;
      GLL(ga + (size_t)(it + 1) * 128, la + nb * 4096);
#pragma unroll
      for (int i = 0; i < 4; ++i)
        GLL(gb[i] + (size_t)(it + 1) * 128, lb[i] + nb * 16384);
    }
    const unsigned short* ab = Ab + buf * 4096;
    const unsigned short* b0p = Bb0 + buf * 16384;
    const unsigned short* b1p = Bb1 + buf * 16384;
#pragma unroll
    for (int ks = 0; ks < 4; ++ks) {
      short8 a = *(const short8*)(ab + ((((ks << 2) | fq) ^ arm) << 3));
      short8 b0 = *(const short8*)(b0p + ((((ks << 2) | fq) ^ nm0) << 3));
      short8 b1 = *(const short8*)(b1p + ((((ks << 2) | fq) ^ nm1) << 3));
      acc0 = __builtin_amdgcn_mfma_f32_16x16x32_bf16(a, b0, acc0, 0, 0, 0);
      acc1 = __builtin_amdgcn_mfma_f32_16x16x32_bf16(a, b1, acc1, 0, 0, 0);
    }
  }

  __syncthreads();
  {
    float u0 = tm[wc * 32 + fr];
    float u1 = tm[wc * 32 + fr + 16];
#pragma unroll
    for (int ii = 0; ii < 4; ++ii) {
      Ts[wr * 16 + fq * 4 + ii][wc * 32 + fr] = acc0[ii] - u0;
      Ts[wr * 16 + fq * 4 + ii][wc * 32 + fr + 16] = acc1[ii] - u1;
    }
  }
  if (t < 32) rs[t] = ssq[r0 + t] - 2.f * xmu[r0 + t] + scal[2];
  __syncthreads();

  int row = t >> 4, cg = t & 15;
  int c0 = cg * 8;
  float y[8] = {0, 0, 0, 0, 0, 0, 0, 0};
#pragma unroll 4
  for (int j = 0; j < 128; ++j) {
    float tv = Ts[row][j];
    float4 v0 = *(const float4*)(Minv + j * LATENT + c0);
    float4 v1 = *(const float4*)(Minv + j * LATENT + c0 + 4);
    y[0] = fmaf(tv, v0.x, y[0]); y[1] = fmaf(tv, v0.y, y[1]);
    y[2] = fmaf(tv, v0.z, y[2]); y[3] = fmaf(tv, v0.w, y[3]);
    y[4] = fmaf(tv, v1.x, y[4]); y[5] = fmaf(tv, v1.y, y[5]);
    y[6] = fmaf(tv, v1.z, y[6]); y[7] = fmaf(tv, v1.w, y[7]);
  }
  float q = 0.f;
#pragma unroll
  for (int c = 0; c < 8; ++c) q = fmaf(y[c], Ts[row][c0 + c], q);
  q += __shfl_xor(q, 1); q += __shfl_xor(q, 2);
  q += __shfl_xor(q, 4); q += __shfl_xor(q, 8);
  if (cg == 0)
    out[r0 + row] = scal[0] - 0.5f * scal[1] * (rs[row] - q);
}

// ---------------------------------------------------------------------------
extern "C" void kernel_launch(void* const* d_in, const int* in_sizes, int n_in,
                              void* d_out, int out_size, void* d_ws, size_t ws_size,
                              hipStream_t stream) {
  (void)in_sizes; (void)n_in; (void)out_size; (void)ws_size;
  const float* ex   = (const float*)d_in[0];
  const float* W    = (const float*)d_in[1];
  const float* lv   = (const float*)d_in[2];
  const float* mean = (const float*)d_in[3];
  float* out = (float*)d_out;

  // ws layout (floats): M 16384 | scal 64 | tmu 128 | ssq 8192 | xmu 8192 |
  //                     then Wt (128*3072 bf16) | Xb (8192*3072 bf16)
  float* M = (float*)d_ws;
  float* scal = M + 16384;
  float* tmu = scal + 64;
  float* ssq = tmu + 128;
  float* xmu = ssq + 8192;
  unsigned short* Wt = (unsigned short*)(xmu + 8192);
  unsigned short* Xb = Wt + (size_t)128 * N_FEAT;

  hipMemsetAsync(M, 0, (size_t)(16384 + 64 + 128) * sizeof(float), stream);
  k_prep<<<48, 256, 0, stream>>>(W, mean, M, Wt, tmu, scal);
  k_packinv<<<1025, 512, 0, stream>>>(ex, mean, Xb, ssq, xmu, M, scal, lv);
  k_gemm<<<256, 512, 0, stream>>>(Xb, Wt, M, ssq, xmu, tmu, scal, out);
}

// Round 7
// 285.134 us; speedup vs baseline: 1.0391x; 1.0391x over previous
//
#include <hip/hip_runtime.h>
#include <hip/hip_bf16.h>

#define N_FEAT 3072
#define LATENT 128
#define LOG2PI 1.8378770664093453f

typedef __attribute__((ext_vector_type(8))) short short8;
typedef __attribute__((ext_vector_type(4))) float f32x4;

__device__ __forceinline__ unsigned short f2bf(float x) {
  unsigned int u = __float_as_uint(x);
  u += 0x7FFFu + ((u >> 16) & 1u);
  return (unsigned short)(u >> 16);
}

// async global->LDS DMA, 16B per lane; lds base must be wave-uniform
#define GLL(g, l)                                                        \
  __builtin_amdgcn_global_load_lds(                                      \
      (__attribute__((address_space(1))) void*)(g),                      \
      (__attribute__((address_space(3))) void*)(l), 16, 0, 0)

// ---------------------------------------------------------------------------
// k_prep: (a) M += Wchunk^T Wchunk (atomics, M pre-zeroed)
//         (b) Wt[n][k] = bf16(W[k][n])
//         (c) tmu[j] += sum_k W[k][j]*mean[k];  scal[2] += sum mean^2
// 48 blocks x 64 k-rows; W read once.  (proven round 4/5/6)
// ---------------------------------------------------------------------------
#define GR_CHUNK 64
__global__ __launch_bounds__(256) void k_prep(const float* __restrict__ W,
                                              const float* __restrict__ mean,
                                              float* __restrict__ M,
                                              unsigned short* __restrict__ Wt,
                                              float* __restrict__ tmu,
                                              float* __restrict__ scal) {
  __shared__ __align__(16) float Ws[GR_CHUNK * 128];
  int t = threadIdx.x;
  int k0 = blockIdx.x * GR_CHUNK;
  const float* src = W + (size_t)k0 * 128;
#pragma unroll
  for (int c = 0; c < 8; ++c)
    ((float4*)Ws)[t + 256 * c] = ((const float4*)src)[t + 256 * c];
  __syncthreads();
  int tr = t >> 4, tc = t & 15;
  float acc[8][8];
#pragma unroll
  for (int r = 0; r < 8; ++r)
#pragma unroll
    for (int c = 0; c < 8; ++c) acc[r][c] = 0.f;
#pragma unroll 2
  for (int k = 0; k < GR_CHUNK; ++k) {
    f32x4 a0 = *(f32x4*)&Ws[k * 128 + 8 * tr];
    f32x4 a1 = *(f32x4*)&Ws[k * 128 + 8 * tr + 4];
    f32x4 b0 = *(f32x4*)&Ws[k * 128 + 8 * tc];
    f32x4 b1 = *(f32x4*)&Ws[k * 128 + 8 * tc + 4];
    float av[8] = {a0.x, a0.y, a0.z, a0.w, a1.x, a1.y, a1.z, a1.w};
    float bv[8] = {b0.x, b0.y, b0.z, b0.w, b1.x, b1.y, b1.z, b1.w};
#pragma unroll
    for (int r = 0; r < 8; ++r)
#pragma unroll
      for (int c = 0; c < 8; ++c) acc[r][c] = fmaf(av[r], bv[c], acc[r][c]);
  }
  float* dst = M + (size_t)(8 * tr) * 128 + 8 * tc;
#pragma unroll
  for (int r = 0; r < 8; ++r)
#pragma unroll
    for (int c = 0; c < 8; ++c) atomicAdd(&dst[r * 128 + c], acc[r][c]);
  int n = t >> 1, h = t & 1;
  unsigned pk[16];
#pragma unroll
  for (int c = 0; c < 16; ++c)
    pk[c] = (unsigned)f2bf(Ws[(h * 32 + 2 * c) * 128 + n]) |
            ((unsigned)f2bf(Ws[(h * 32 + 2 * c + 1) * 128 + n]) << 16);
  uint4* wd = (uint4*)(Wt + (size_t)n * N_FEAT + k0 + h * 32);
#pragma unroll
  for (int c = 0; c < 4; ++c)
    wd[c] = make_uint4(pk[4 * c], pk[4 * c + 1], pk[4 * c + 2], pk[4 * c + 3]);
  if (t < 128) {
    float tm = 0.f;
#pragma unroll 8
    for (int k = 0; k < GR_CHUNK; ++k)
      tm = fmaf(Ws[k * 128 + t], mean[k0 + k], tm);
    atomicAdd(&tmu[t], tm);
  } else if (t == 128) {
    float s = 0.f;
#pragma unroll 8
    for (int k = 0; k < GR_CHUNK; ++k) {
      float m = mean[k0 + k];
      s = fmaf(m, m, s);
    }
    atomicAdd(&scal[2], s);
  }
}

// ---------------------------------------------------------------------------
// k_packinv (512 thr): blocks 0..1023: pack 8 rows each (Xb, ssq, xmu).
//   block 1024: blocked Gauss-Jordan inverse, SPILL-FREE version:
//   - Rp's pivot-block columns get identity substituted -> Rp pivot cols hold
//     Pinv directly; P's liveness ends at phase 2 (no P in fixups).
//   - phase 2 runs on t<256 only (the P consumers).
//   - phase 3 streams CsT/Rp from LDS per-m (12 live floats, broadcasts),
//     fixup tiles load directly from Rp/CpT and skip the update.
// ---------------------------------------------------------------------------
__global__ __launch_bounds__(512) void k_packinv(const float* __restrict__ ex,
                                                 const float* __restrict__ mean,
                                                 unsigned short* __restrict__ Xb,
                                                 float* __restrict__ ssq,
                                                 float* __restrict__ xmu,
                                                 float* __restrict__ M,
                                                 float* __restrict__ scal,
                                                 const float* __restrict__ log_var) {
  int t = threadIdx.x;
  if (blockIdx.x == 1024) {
    // ---------------- blocked inverse path ----------------
    __shared__ __align__(16) float Rs[8][128];    // raw pivot rows
    __shared__ __align__(16) float Rp[8][128];    // Pinv*R (pivot cols = Pinv)
    __shared__ __align__(16) float CsT[8][136];   // raw pivot cols, transposed
    __shared__ __align__(16) float CpT[8][136];   // -(C*Pinv), transposed
    __shared__ float diag[128];
    __shared__ float red[2];
    int tr = t >> 5;   // 0..15 : rows 8tr..8tr+7
    int tc = t & 31;   // 0..31 : cols 4tc..4tc+3
    float lv = log_var[0];
    float sig2 = expf(lv);
    float a[8][4];
    const float* srcM = M + (size_t)(8 * tr) * 128 + 4 * tc;
#pragma unroll
    for (int r = 0; r < 8; ++r) {
      f32x4 v = *(const f32x4*)(srcM + r * 128);
      a[r][0] = v.x; a[r][1] = v.y; a[r][2] = v.z; a[r][3] = v.w;
    }
#pragma unroll
    for (int r = 0; r < 8; ++r)
#pragma unroll
      for (int c = 0; c < 4; ++c)
        if (8 * tr + r == 4 * tc + c) a[r][c] += sig2;

    for (int kb = 0; kb < 16; ++kb) {
      // ---- phase 1: stage raw pivot rows/cols ----
      if (tr == kb) {
#pragma unroll
        for (int r = 0; r < 8; ++r)
          *(f32x4*)&Rs[r][4 * tc] = (f32x4){a[r][0], a[r][1], a[r][2], a[r][3]};
      }
      if ((tc >> 1) == kb) {
        int jb = (tc & 1) * 4;
#pragma unroll
        for (int r = 0; r < 8; ++r)
#pragma unroll
          for (int c = 0; c < 4; ++c) CsT[jb + c][8 * tr + r] = a[r][c];
      }
      __syncthreads();
      // ---- phase 2 (t<256 only): redundant 8x8 pivot inverse + Rp/CpT ----
      if (t < 256) {
        float P[8][8];
#pragma unroll
        for (int i = 0; i < 8; ++i) {
          f32x4 p0 = *(const f32x4*)&Rs[i][8 * kb];
          f32x4 p1 = *(const f32x4*)&Rs[i][8 * kb + 4];
          P[i][0] = p0.x; P[i][1] = p0.y; P[i][2] = p0.z; P[i][3] = p0.w;
          P[i][4] = p1.x; P[i][5] = p1.y; P[i][6] = p1.z; P[i][7] = p1.w;
        }
#pragma unroll
        for (int i = 0; i < 8; ++i) {
          float d = P[i][i];
          if (t == 0) diag[8 * kb + i] = d;
          float pi = 1.0f / d;
          P[i][i] = 1.0f;
#pragma unroll
          for (int c = 0; c < 8; ++c) P[i][c] *= pi;
#pragma unroll
          for (int r = 0; r < 8; ++r) {
            if (r == i) continue;
            float e = P[r][i];
            P[r][i] = 0.0f;
#pragma unroll
            for (int c = 0; c < 8; ++c) P[r][c] = fmaf(-e, P[i][c], P[r][c]);
          }
        }
        if (t < 128) {
          // Rp col t = Pinv * (R col t), with identity substituted for
          // pivot-block columns so Rp pivot cols = Pinv itself.
          float rcol[8];
          int jl = t - 8 * kb;
#pragma unroll
          for (int m = 0; m < 8; ++m) rcol[m] = Rs[m][t];
          if (jl >= 0 && jl < 8) {
#pragma unroll
            for (int m = 0; m < 8; ++m) rcol[m] = (m == jl) ? 1.0f : 0.0f;
          }
#pragma unroll
          for (int i = 0; i < 8; ++i) {
            float s = 0.f;
#pragma unroll
            for (int m = 0; m < 8; ++m) s = fmaf(P[i][m], rcol[m], s);
            Rp[i][t] = s;
          }
        } else {
          int r = t - 128;
          float crow[8];
#pragma unroll
          for (int m = 0; m < 8; ++m) crow[m] = CsT[m][r];
#pragma unroll
          for (int j = 0; j < 8; ++j) {
            float s = 0.f;
#pragma unroll
            for (int m = 0; m < 8; ++m) s = fmaf(crow[m], P[m][j], s);
            CpT[j][r] = -s;
          }
        }
      }
      __syncthreads();
      // ---- phase 3: fixups load from LDS; others rank-8 update (streamed) --
      if (tr == kb) {
#pragma unroll
        for (int r = 0; r < 8; ++r) {
          f32x4 rv = *(const f32x4*)&Rp[r][4 * tc];
          a[r][0] = rv.x; a[r][1] = rv.y; a[r][2] = rv.z; a[r][3] = rv.w;
        }
      } else if ((tc >> 1) == kb) {
        int jb = (tc & 1) * 4;
#pragma unroll
        for (int r = 0; r < 8; ++r)
#pragma unroll
          for (int c = 0; c < 4; ++c) a[r][c] = CpT[jb + c][8 * tr + r];
      } else {
#pragma unroll
        for (int m = 0; m < 8; ++m) {
          f32x4 cv0 = *(const f32x4*)&CsT[m][8 * tr];
          f32x4 cv1 = *(const f32x4*)&CsT[m][8 * tr + 4];
          f32x4 rv = *(const f32x4*)&Rp[m][4 * tc];
          float cl[8] = {cv0.x, cv0.y, cv0.z, cv0.w,
                         cv1.x, cv1.y, cv1.z, cv1.w};
          float rp4[4] = {rv.x, rv.y, rv.z, rv.w};
#pragma unroll
          for (int r = 0; r < 8; ++r)
#pragma unroll
            for (int c = 0; c < 4; ++c)
              a[r][c] = fmaf(-cl[r], rp4[c], a[r][c]);
        }
      }
      __syncthreads();
    }

    float* dstM = M + (size_t)(8 * tr) * 128 + 4 * tc;
#pragma unroll
    for (int r = 0; r < 8; ++r)
      *(f32x4*)(dstM + r * 128) = (f32x4){a[r][0], a[r][1], a[r][2], a[r][3]};
    // parallel logdet
    float ld = 0.f;
    if (t < 128) ld = logf(diag[t]);
#pragma unroll
    for (int o = 1; o < 64; o <<= 1) ld += __shfl_xor(ld, o);
    if (t == 0) red[0] = ld;
    if (t == 64) red[1] = ld;
    __syncthreads();
    if (t == 0) {
      scal[0] = -0.5f * (N_FEAT * LOG2PI + (float)(N_FEAT - LATENT) * lv +
                         (red[0] + red[1]));
      scal[1] = expf(-lv);
    }
    return;
  }

  // ---------------- pack path (streaming, barrier-free) ----------------
  int w = t >> 6, l = t & 63;
  int row = blockIdx.x * 8 + w;
  const float* xp = ex + (size_t)row * N_FEAT;
  unsigned short* op = Xb + (size_t)row * N_FEAT;
  float sq = 0.f, dm = 0.f;
#pragma unroll
  for (int c = 0; c < 6; ++c) {
    int off = c * 512 + l * 8;
    float4 x0 = *(const float4*)(xp + off);
    float4 x1 = *(const float4*)(xp + off + 4);
    float4 m0 = *(const float4*)(mean + off);
    float4 m1 = *(const float4*)(mean + off + 4);
    sq = fmaf(x0.x, x0.x, sq); sq = fmaf(x0.y, x0.y, sq);
    sq = fmaf(x0.z, x0.z, sq); sq = fmaf(x0.w, x0.w, sq);
    sq = fmaf(x1.x, x1.x, sq); sq = fmaf(x1.y, x1.y, sq);
    sq = fmaf(x1.z, x1.z, sq); sq = fmaf(x1.w, x1.w, sq);
    dm = fmaf(x0.x, m0.x, dm); dm = fmaf(x0.y, m0.y, dm);
    dm = fmaf(x0.z, m0.z, dm); dm = fmaf(x0.w, m0.w, dm);
    dm = fmaf(x1.x, m1.x, dm); dm = fmaf(x1.y, m1.y, dm);
    dm = fmaf(x1.z, m1.z, dm); dm = fmaf(x1.w, m1.w, dm);
    uint4 pk;
    pk.x = (unsigned)f2bf(x0.x) | ((unsigned)f2bf(x0.y) << 16);
    pk.y = (unsigned)f2bf(x0.z) | ((unsigned)f2bf(x0.w) << 16);
    pk.z = (unsigned)f2bf(x1.x) | ((unsigned)f2bf(x1.y) << 16);
    pk.w = (unsigned)f2bf(x1.z) | ((unsigned)f2bf(x1.w) << 16);
    *(uint4*)(op + off) = pk;
  }
#pragma unroll
  for (int o = 1; o < 64; o <<= 1) {
    sq += __shfl_xor(sq, o);
    dm += __shfl_xor(dm, o);
  }
  if (l == 0) {
    ssq[row] = sq;
    xmu[row] = dm;
  }
}

// ---------------------------------------------------------------------------
// k_gemm: T-tile = Xb * Wt^T (m97-style DMA K-loop) + fused quad epilogue.
// (unchanged from round 5/6)
// ---------------------------------------------------------------------------
__global__ __launch_bounds__(512) void k_gemm(const unsigned short* __restrict__ Xb,
                                              const unsigned short* __restrict__ Wt,
                                              const float* __restrict__ Minv,
                                              const float* __restrict__ ssq,
                                              const float* __restrict__ xmu,
                                              const float* __restrict__ tmu,
                                              const float* __restrict__ scal,
                                              float* __restrict__ out) {
  __shared__ __align__(16) unsigned short As[2][32][128];
  __shared__ __align__(16) unsigned short Bs[2][128][128];
  __shared__ __align__(16) float Ts[32][132];
  __shared__ float tm[128];
  __shared__ float rs[32];
  int t = threadIdx.x;
  int l = t & 63, w = t >> 6;
  int wr = w & 1, wc = w >> 1;
  int fr = l & 15, fq = l >> 4;
  int r0 = blockIdx.x * 32;
  int lr = l >> 4, lk = l & 15;

  if (t < 128) tm[t] = tmu[t];

  int arow = 4 * w + lr;
  const unsigned short* ga =
      Xb + (size_t)(r0 + arow) * N_FEAT + (lk ^ (arow & 7)) * 8;
  unsigned short* la = &As[0][4 * w][0];
  const unsigned short* gb[4];
  unsigned short* lb[4];
#pragma unroll
  for (int i = 0; i < 4; ++i) {
    int br = 4 * w + 32 * i + lr;
    gb[i] = Wt + (size_t)br * N_FEAT + (lk ^ (br & 7)) * 8;
    lb[i] = &Bs[0][4 * w + 32 * i][0];
  }

  GLL(ga, la);
#pragma unroll
  for (int i = 0; i < 4; ++i) GLL(gb[i], lb[i]);

  int ar = wr * 16 + fr;
  int arm = ar & 7;
  int n0 = wc * 32 + fr, n1 = n0 + 16;
  int nm0 = n0 & 7, nm1 = n1 & 7;
  const unsigned short* Ab = &As[0][ar][0];
  const unsigned short* Bb0 = &Bs[0][n0][0];
  const unsigned short* Bb1 = &Bs[0][n1][0];

  f32x4 acc0 = {0.f, 0.f, 0.f, 0.f}, acc1 = {0.f, 0.f, 0.f, 0.f};

  for (int it = 0; it < 24; ++it) {
    const int buf = it & 1;
    __syncthreads();
    if (it + 1 < 24) {
      const int nb = buf ^ 1;
      GLL(ga + (size_t)(it + 1) * 128, la + nb * 4096);
#pragma unroll
      for (int i = 0; i < 4; ++i)
        GLL(gb[i] + (size_t)(it + 1) * 128, lb[i] + nb * 16384);
    }
    const unsigned short* ab = Ab + buf * 4096;
    const unsigned short* b0p = Bb0 + buf * 16384;
    const unsigned short* b1p = Bb1 + buf * 16384;
#pragma unroll
    for (int ks = 0; ks < 4; ++ks) {
      short8 a = *(const short8*)(ab + ((((ks << 2) | fq) ^ arm) << 3));
      short8 b0 = *(const short8*)(b0p + ((((ks << 2) | fq) ^ nm0) << 3));
      short8 b1 = *(const short8*)(b1p + ((((ks << 2) | fq) ^ nm1) << 3));
      acc0 = __builtin_amdgcn_mfma_f32_16x16x32_bf16(a, b0, acc0, 0, 0, 0);
      acc1 = __builtin_amdgcn_mfma_f32_16x16x32_bf16(a, b1, acc1, 0, 0, 0);
    }
  }

  __syncthreads();
  {
    float u0 = tm[wc * 32 + fr];
    float u1 = tm[wc * 32 + fr + 16];
#pragma unroll
    for (int ii = 0; ii < 4; ++ii) {
      Ts[wr * 16 + fq * 4 + ii][wc * 32 + fr] = acc0[ii] - u0;
      Ts[wr * 16 + fq * 4 + ii][wc * 32 + fr + 16] = acc1[ii] - u1;
    }
  }
  if (t < 32) rs[t] = ssq[r0 + t] - 2.f * xmu[r0 + t] + scal[2];
  __syncthreads();

  int row = t >> 4, cg = t & 15;
  int c0 = cg * 8;
  float y[8] = {0, 0, 0, 0, 0, 0, 0, 0};
#pragma unroll 4
  for (int j = 0; j < 128; ++j) {
    float tv = Ts[row][j];
    float4 v0 = *(const float4*)(Minv + j * LATENT + c0);
    float4 v1 = *(const float4*)(Minv + j * LATENT + c0 + 4);
    y[0] = fmaf(tv, v0.x, y[0]); y[1] = fmaf(tv, v0.y, y[1]);
    y[2] = fmaf(tv, v0.z, y[2]); y[3] = fmaf(tv, v0.w, y[3]);
    y[4] = fmaf(tv, v1.x, y[4]); y[5] = fmaf(tv, v1.y, y[5]);
    y[6] = fmaf(tv, v1.z, y[6]); y[7] = fmaf(tv, v1.w, y[7]);
  }
  float q = 0.f;
#pragma unroll
  for (int c = 0; c < 8; ++c) q = fmaf(y[c], Ts[row][c0 + c], q);
  q += __shfl_xor(q, 1); q += __shfl_xor(q, 2);
  q += __shfl_xor(q, 4); q += __shfl_xor(q, 8);
  if (cg == 0)
    out[r0 + row] = scal[0] - 0.5f * scal[1] * (rs[row] - q);
}

// ---------------------------------------------------------------------------
extern "C" void kernel_launch(void* const* d_in, const int* in_sizes, int n_in,
                              void* d_out, int out_size, void* d_ws, size_t ws_size,
                              hipStream_t stream) {
  (void)in_sizes; (void)n_in; (void)out_size; (void)ws_size;
  const float* ex   = (const float*)d_in[0];
  const float* W    = (const float*)d_in[1];
  const float* lv   = (const float*)d_in[2];
  const float* mean = (const float*)d_in[3];
  float* out = (float*)d_out;

  // ws layout (floats): M 16384 | scal 64 | tmu 128 | ssq 8192 | xmu 8192 |
  //                     then Wt (128*3072 bf16) | Xb (8192*3072 bf16)
  float* M = (float*)d_ws;
  float* scal = M + 16384;
  float* tmu = scal + 64;
  float* ssq = tmu + 128;
  float* xmu = ssq + 8192;
  unsigned short* Wt = (unsigned short*)(xmu + 8192);
  unsigned short* Xb = Wt + (size_t)128 * N_FEAT;

  hipMemsetAsync(M, 0, (size_t)(16384 + 64 + 128) * sizeof(float), stream);
  k_prep<<<48, 256, 0, stream>>>(W, mean, M, Wt, tmu, scal);
  k_packinv<<<1025, 512, 0, stream>>>(ex, mean, Xb, ssq, xmu, M, scal, lv);
  k_gemm<<<256, 512, 0, stream>>>(Xb, Wt, M, ssq, xmu, tmu, scal, out);
}